// Round 10
// baseline (91.174 us; speedup 1.0000x reference)
//
#include <hip/hip_runtime.h>
#include <math.h>

#define BATCH 8
#define NTOK  4096
#define DIM   64
#define BM    128
#define NT    (NTOK / BM)            // 32 tiles per dim
#define TPB   (NT * (NT + 1) / 2)    // 528 upper-tri tile pairs per batch
#define TOTAL (BATCH * TPB)          // 4224 tile-pair blocks
#define KAPPA 0.5f
#define LOG2E 1.4426950408889634f
#define LN2   0.6931471805599453f
// sqrt(KAPPA*LOG2E): image pre-scale so MFMA output IS the log2-domain logit
#define SQRTC2 0.8493218f

typedef _Float16 f16x8 __attribute__((ext_vector_type(8)));
typedef float    f32x16 __attribute__((ext_vector_type(16)));

__device__ __forceinline__ float EXP2(float x) {
#if __has_builtin(__builtin_amdgcn_exp2f)
    return __builtin_amdgcn_exp2f(x);
#else
    return __expf(x * LN2);
#endif
}

// ---- kernel 0: one-time f32 -> f16 image, PRE-SCALED by sqrt(kappa*log2e).
// dot(a',b') = c2 * dot(a,b): the MFMA accumulator comes out directly in the
// log2 domain -> epilogue needs zero VALU besides one add per element.
__global__ __launch_bounds__(256)
void conv_f16(const float* __restrict__ emb, f16x8* __restrict__ o16) {
    const size_t i = (size_t)blockIdx.x * 256 + threadIdx.x;  // 262144 units
    const float4 v0 = *(const float4*)(emb + i * 8);
    const float4 v1 = *(const float4*)(emb + i * 8 + 4);
    f16x8 p;
    p[0] = (_Float16)(v0.x * SQRTC2); p[1] = (_Float16)(v0.y * SQRTC2);
    p[2] = (_Float16)(v0.z * SQRTC2); p[3] = (_Float16)(v0.w * SQRTC2);
    p[4] = (_Float16)(v1.x * SQRTC2); p[5] = (_Float16)(v1.y * SQRTC2);
    p[6] = (_Float16)(v1.z * SQRTC2); p[7] = (_Float16)(v1.w * SQRTC2);
    o16[i] = p;
}

// ---- kernel 1: BARRIER-FREE wave-autonomous gram (R10).
// R8/R9 model: the invariant ~18 us is phase-wall stall (stage -> vmcnt(0)+
// barrier -> MFMA -> barrier -> exp; all waves wait L2 latency together, exp
// bursts saturate the quarter-rate trans pipe in lockstep). Fix: no LDS, no
// barriers. Each wave front-loads its 16 fragments from the L2-resident
// pre-scaled image (independent dwordx4 loads -> natural pipeline), runs 4
// quadrant MFMA chains, folds exp2 immediately. R5 tried global-direct and
// regressed — WITHOUT the XCD swizzle (L2 thrash, +9-11 us, fixed in R6) and
// with late per-fragment loads; both corrected here. No -M2FIX shift: acc is
// already log2-domain, exp2 range [2^-87, 2^87] and partial sums <= 2^99 are
// f32-safe; shift folded into reduce (which now just takes log2f).
__global__ __launch_bounds__(256, 4)
void gram_lse_partial(const f16x8* __restrict__ w16, float* __restrict__ ws) {
    const int tid  = threadIdx.x;
    const int lane = tid & 63;
    const int w    = tid >> 6;
    const int p    = blockIdx.x;
    const int bb   = (p & 7) * TPB + (p >> 3);   // XCD-chunked swizzle (T1)
    const int b    = bb / TPB;                   // == p & 7
    int t = bb - b * TPB;
    int ti = 0;
    while (t >= NT - ti) { t -= NT - ti; ++ti; }
    const int tj = ti + t;

    // panel bases as f16x8 units: unit index = row*8 + g (row stride 128 B)
    const f16x8* pA = w16 + ((size_t)b * NTOK + (size_t)ti * BM) * 8;
    const f16x8* pB = w16 + ((size_t)b * NTOK + (size_t)tj * BM) * 8;

    const int half = lane >> 5;    // k-half within fragment
    const int ln31 = lane & 31;
    const int rA = (w & 1) * 64 + ln31;    // A rows: rA, rA+32
    const int rB = (w >> 1) * 64 + ln31;   // B rows: rB, rB+32

    // ---- front-load all 16 fragments (independent; fully static indices) ----
    f16x8 aL[4], aH[4], bL[4], bH[4];
#pragma unroll
    for (int s = 0; s < 4; ++s) {
        const int g = 2 * s + half;        // k-slice 8g..8g+7
        aL[s] = pA[rA * 8 + g];
        aH[s] = pA[(rA + 32) * 8 + g];
        bL[s] = pB[rB * 8 + g];
        bH[s] = pB[(rB + 32) * 8 + g];
    }

    // ---- 4 quadrants: 4-chain MFMA then immediate exp2 fold (acc reused) ----
    float s0 = 0.f, s1 = 0.f, s2 = 0.f, s3 = 0.f;
    {
        f32x16 acc = {};
#pragma unroll
        for (int s = 0; s < 4; ++s)
            acc = __builtin_amdgcn_mfma_f32_32x32x16_f16(aL[s], bL[s], acc, 0, 0, 0);
#pragma unroll
        for (int e = 0; e < 16; e += 4) {
            s0 += EXP2(acc[e]);     s1 += EXP2(acc[e + 1]);
            s2 += EXP2(acc[e + 2]); s3 += EXP2(acc[e + 3]);
        }
    }
    {
        f32x16 acc = {};
#pragma unroll
        for (int s = 0; s < 4; ++s)
            acc = __builtin_amdgcn_mfma_f32_32x32x16_f16(aL[s], bH[s], acc, 0, 0, 0);
#pragma unroll
        for (int e = 0; e < 16; e += 4) {
            s0 += EXP2(acc[e]);     s1 += EXP2(acc[e + 1]);
            s2 += EXP2(acc[e + 2]); s3 += EXP2(acc[e + 3]);
        }
    }
    {
        f32x16 acc = {};
#pragma unroll
        for (int s = 0; s < 4; ++s)
            acc = __builtin_amdgcn_mfma_f32_32x32x16_f16(aH[s], bL[s], acc, 0, 0, 0);
#pragma unroll
        for (int e = 0; e < 16; e += 4) {
            s0 += EXP2(acc[e]);     s1 += EXP2(acc[e + 1]);
            s2 += EXP2(acc[e + 2]); s3 += EXP2(acc[e + 3]);
        }
    }
    {
        f32x16 acc = {};
#pragma unroll
        for (int s = 0; s < 4; ++s)
            acc = __builtin_amdgcn_mfma_f32_32x32x16_f16(aH[s], bH[s], acc, 0, 0, 0);
#pragma unroll
        for (int e = 0; e < 16; e += 4) {
            s0 += EXP2(acc[e]);     s1 += EXP2(acc[e + 1]);
            s2 += EXP2(acc[e + 2]); s3 += EXP2(acc[e + 3]);
        }
    }

    float lsum = (s0 + s1) + (s2 + s3);
#pragma unroll
    for (int off = 32; off > 0; off >>= 1)
        lsum += __shfl_xor(lsum, off);

    if (lane == 0) {
        const float wgt = (ti == tj) ? 1.f : 2.f;
        ws[4 * (size_t)bb + w] = wgt * lsum;   // logical-bb layout for reduce
    }
}

// ---- kernel 2: 1 block, 8 waves; wave w sums batch w's TPB*4 = 2112 wave
// partials (weights already applied). No shift needed: partials are plain
// sums of exp2(log2-domain logits), f32-safe by range analysis.
__global__ __launch_bounds__(512)
void reduce_lse(const float* __restrict__ ws, float* __restrict__ out) {
    const int tid  = threadIdx.x;
    const int w    = tid >> 6;
    const int lane = tid & 63;
    __shared__ float lse8[BATCH];

    const float* p = ws + (size_t)w * TPB * 4;   // batch w: 2112 floats
    float s = 0.f;
#pragma unroll
    for (int c = 0; c < 33; ++c) s += p[lane + 64 * c];
#pragma unroll
    for (int off = 32; off > 0; off >>= 1) s += __shfl_xor(s, off);

    if (lane == 0) lse8[w] = LN2 * log2f(s);     // natural-log LSE
    __syncthreads();
    if (tid == 0) {
        float a = 0.f;
        for (int i = 0; i < BATCH; ++i) a += lse8[i];
        out[0] = a * (1.f / BATCH);
    }
}

extern "C" void kernel_launch(void* const* d_in, const int* in_sizes, int n_in,
                              void* d_out, int out_size, void* d_ws, size_t ws_size,
                              hipStream_t stream) {
    const float* emb = (const float*)d_in[0];
    float* out = (float*)d_out;
    f16x8* w16 = (f16x8*)d_ws;                            // 4 MB f16 image
    float* prt = (float*)((char*)d_ws + (4u << 20));      // 67,584 B partials

    conv_f16<<<NTOK * BATCH * DIM / 8 / 256, 256, 0, stream>>>(emb, w16);
    gram_lse_partial<<<TOTAL, 256, 0, stream>>>(w16, prt);
    reduce_lse<<<1, 512, 0, stream>>>(prt, out);
}

// Round 11
// 77.935 us; speedup vs baseline: 1.1699x; 1.1699x over previous
//
#include <hip/hip_runtime.h>
#include <math.h>

#define BATCH 8
#define NTOK  4096
#define DIM   64
#define BM    128
#define NT    (NTOK / BM)            // 32 tiles per dim
#define TPB   (NT * (NT + 1) / 2)    // 528 upper-tri tile pairs per batch
#define TOTAL (BATCH * TPB)          // 4224 tile-pair blocks
#define KAPPA 0.5f
#define LOG2E 1.4426950408889634f
#define LN2   0.6931471805599453f
// sqrt(KAPPA*LOG2E): image pre-scale so MFMA output IS the log2-domain logit
#define SQRTC2 0.8493218f

typedef _Float16 f16x8 __attribute__((ext_vector_type(8)));
typedef float    f32x16 __attribute__((ext_vector_type(16)));

__device__ __forceinline__ float EXP2(float x) {
#if __has_builtin(__builtin_amdgcn_exp2f)
    return __builtin_amdgcn_exp2f(x);
#else
    return __expf(x * LN2);
#endif
}

// ---- kernel 0: one-time f32 -> f16 image, PRE-SCALED by sqrt(kappa*log2e)
// (R10's one proven-good idea): dot(a',b') = kappa*log2e*dot(a,b), so the
// MFMA accumulator is directly the log2-domain logit -> epilogue is
// exp2 + add only (half the VALU of the fmaf version). f16 dynamic range is
// fine: values scale by 0.849.
__global__ __launch_bounds__(256)
void conv_f16(const float* __restrict__ emb, f16x8* __restrict__ o16) {
    const size_t i = (size_t)blockIdx.x * 256 + threadIdx.x;  // 262144 units
    const float4 v0 = *(const float4*)(emb + i * 8);
    const float4 v1 = *(const float4*)(emb + i * 8 + 4);
    f16x8 p;
    p[0] = (_Float16)(v0.x * SQRTC2); p[1] = (_Float16)(v0.y * SQRTC2);
    p[2] = (_Float16)(v0.z * SQRTC2); p[3] = (_Float16)(v0.w * SQRTC2);
    p[4] = (_Float16)(v1.x * SQRTC2); p[5] = (_Float16)(v1.y * SQRTC2);
    p[6] = (_Float16)(v1.z * SQRTC2); p[7] = (_Float16)(v1.w * SQRTC2);
    o16[i] = p;
}

// ---- kernel 1: gram (R11 = best-of-all-rounds recombination).
// Ablation ledger: LDS-DMA staging beats global-direct (R5, R10: +9-11 us
// from 2x L2 traffic); XCD-chunked swizzle worth ~9-11 us on this traffic
// (R5 vs R6); 5 blocks/CU > 4 (R9, LDS-bound at 160 KB exact — registers
// were never the limiter, 128 regs < 409 available at 5 waves/SIMD); 4-acc
// MFMA block halves ds_read_b128 count vs R9's quadrant loop (16 vs 32/wave)
// and issues 4 independent MFMA chains. Epilogue: prescaled image -> acc is
// log2-domain -> exp2 + add only, no fmaf, no M2FIX.
__global__ __launch_bounds__(256, 5)
void gram_lse_partial(const f16x8* __restrict__ w16, float* __restrict__ ws) {
    __shared__ f16x8 S[2048];      // 32 KB: As = S[0..1023], Bs = S[1024..2047]

    const int tid  = threadIdx.x;
    const int lane = tid & 63;
    const int w    = tid >> 6;
    const int p    = blockIdx.x;
    const int bb   = (p & 7) * TPB + (p >> 3);   // XCD-chunked swizzle (T1)
    const int b    = bb / TPB;                   // == p & 7
    int t = bb - b * TPB;
    int ti = 0;
    while (t >= NT - ti) { t -= NT - ti; ++ti; }
    const int tj = ti + t;

    const char* pA16 = (const char*)(w16 + ((size_t)b * NTOK + (size_t)ti * BM) * 8);
    const char* pB16 = (const char*)(w16 + ((size_t)b * NTOK + (size_t)tj * BM) * 8);

    // ---- staging: 8 global_load_lds_dwordx4 per thread (verified R3-R9) ----
    // LDS dest linear (wave-uniform base + lane*16); XOR swizzle realized on
    // the per-lane GLOBAL source address (rule 21).
    {
        const char* pbase  = (w < 2) ? pA16 : pB16;     // wave-uniform
        const int   upBase = (w & 1) * 512 + lane;
#pragma unroll
        for (int q = 0; q < 8; ++q) {
            const int up  = upBase + q * 64;
            const int g   = up >> 7;
            const int rp  = up & 127;
            const int off = (((rp ^ g) << 7) | (g << 4));
            __builtin_amdgcn_global_load_lds(
                (const __attribute__((address_space(1))) void*)(pbase + off),
                (__attribute__((address_space(3))) void*)&S[(size_t)w * 512 + q * 64],
                16, 0, 0);
        }
    }
    __syncthreads();   // compiler emits vmcnt(0) drain before s_barrier

    // ---- MFMA: wave computes a 64x64 subtile (2x2 of 32x32, K=64);
    // 16 ds_read_b128, 4 independent MFMA chains ----
    const int half = lane >> 5;    // k-half within fragment
    const int ln31 = lane & 31;
    const int waveR = (w & 1) * 64;
    const int waveC = (w >> 1) * 64;

    f32x16 acc00 = {}, acc01 = {}, acc10 = {}, acc11 = {};
#pragma unroll
    for (int s = 0; s < 4; ++s) {
        const int g = 2 * s + half;
        const f16x8 a0 = S[g * BM + ((waveR + ln31) ^ g)];
        const f16x8 a1 = S[g * BM + ((waveR + 32 + ln31) ^ g)];
        const f16x8 b0 = S[1024 + g * BM + ((waveC + ln31) ^ g)];
        const f16x8 b1 = S[1024 + g * BM + ((waveC + 32 + ln31) ^ g)];
        acc00 = __builtin_amdgcn_mfma_f32_32x32x16_f16(a0, b0, acc00, 0, 0, 0);
        acc01 = __builtin_amdgcn_mfma_f32_32x32x16_f16(a0, b1, acc01, 0, 0, 0);
        acc10 = __builtin_amdgcn_mfma_f32_32x32x16_f16(a1, b0, acc10, 0, 0, 0);
        acc11 = __builtin_amdgcn_mfma_f32_32x32x16_f16(a1, b1, acc11, 0, 0, 0);
    }

    // ---- epilogue: acc IS the log2-domain logit -> exp2 + add only ----
    float s0 = 0.f, s1 = 0.f, s2 = 0.f, s3 = 0.f;
#pragma unroll
    for (int e = 0; e < 16; ++e) {
        s0 += EXP2(acc00[e]);
        s1 += EXP2(acc01[e]);
        s2 += EXP2(acc10[e]);
        s3 += EXP2(acc11[e]);
    }
    float lsum = (s0 + s1) + (s2 + s3);
#pragma unroll
    for (int off = 32; off > 0; off >>= 1)
        lsum += __shfl_xor(lsum, off);

    if (lane == 0) {
        const float wgt = (ti == tj) ? 1.f : 2.f;
        ws[4 * (size_t)bb + w] = wgt * lsum;   // logical-bb layout for reduce
    }
}

// ---- kernel 2: 1 block, 8 waves; wave w sums batch w's TPB*4 = 2112 wave
// partials (weights already applied). Partials are plain sums of
// exp2(log2-domain logits); range analysis (R10): sums <= 2^99, f32-safe.
__global__ __launch_bounds__(512)
void reduce_lse(const float* __restrict__ ws, float* __restrict__ out) {
    const int tid  = threadIdx.x;
    const int w    = tid >> 6;
    const int lane = tid & 63;
    __shared__ float lse8[BATCH];

    const float* p = ws + (size_t)w * TPB * 4;   // batch w: 2112 floats
    float s = 0.f;
#pragma unroll
    for (int c = 0; c < 33; ++c) s += p[lane + 64 * c];
#pragma unroll
    for (int off = 32; off > 0; off >>= 1) s += __shfl_xor(s, off);

    if (lane == 0) lse8[w] = LN2 * log2f(s);     // natural-log LSE
    __syncthreads();
    if (tid == 0) {
        float a = 0.f;
        for (int i = 0; i < BATCH; ++i) a += lse8[i];
        out[0] = a * (1.f / BATCH);
    }
}

extern "C" void kernel_launch(void* const* d_in, const int* in_sizes, int n_in,
                              void* d_out, int out_size, void* d_ws, size_t ws_size,
                              hipStream_t stream) {
    const float* emb = (const float*)d_in[0];
    float* out = (float*)d_out;
    f16x8* w16 = (f16x8*)d_ws;                            // 4 MB f16 image
    float* prt = (float*)((char*)d_ws + (4u << 20));      // 67,584 B partials

    conv_f16<<<NTOK * BATCH * DIM / 8 / 256, 256, 0, stream>>>(emb, w16);
    gram_lse_partial<<<TOTAL, 256, 0, stream>>>(w16, prt);
    reduce_lse<<<1, 512, 0, stream>>>(prt, out);
}

// Round 12
// 76.261 us; speedup vs baseline: 1.1956x; 1.0220x over previous
//
#include <hip/hip_runtime.h>
#include <math.h>

#define BATCH 8
#define NTOK  4096
#define DIM   64
#define BM    128
#define NT    (NTOK / BM)            // 32 tiles per dim
#define TPB   (NT * (NT + 1) / 2)    // 528 upper-tri tile pairs per batch
#define TOTAL (BATCH * TPB)          // 4224 tile-pair blocks
#define KAPPA 0.5f
#define LOG2E 1.4426950408889634f
#define LN2   0.6931471805599453f
// sqrt(KAPPA*LOG2E): staging pre-scale so MFMA output IS the log2-domain logit
#define SQRTC2 0.8493218f

typedef _Float16 f16x8 __attribute__((ext_vector_type(8)));
typedef float    f32x16 __attribute__((ext_vector_type(16)));

__device__ __forceinline__ float EXP2(float x) {
#if __has_builtin(__builtin_amdgcn_exp2f)
    return __builtin_amdgcn_exp2f(x);
#else
    return __expf(x * LN2);
#endif
}

// ---- kernel 1: gram, conv node eliminated (R12).
// Budget model (R8-calibrated): 77.9 = fill 41.5 (harness-fixed) + conv 2.5
// + gram ~17 + reduce 2.5 + ~14 us node-boundary overhead (~3-5 us/node).
// R2-vs-R3 proved in-block f32->f16 cvt staging == DMA staging in time, so
// the f16-image conv node only costs a node. Fold cvt (+ SQRTC2 prescale)
// back into staging; 4 nodes -> 3 (fill, gram, reduce).
// Retained ledger: XOR-swizzled LDS (0 conflicts), XCD-chunked block swizzle
// (R5/R6: worth ~9-11 us), 4-acc MFMA block (16 ds_read_b128, 4 indep MFMA
// chains), exp2-only epilogue (prescale; R10/R11 verified numerics),
// (256,5): 5 blocks/CU, LDS 160 KB exact.
__global__ __launch_bounds__(256, 5)
void gram_lse_partial(const float* __restrict__ emb, float* __restrict__ ws) {
    // Panels as 16-B units: unit (g, row) at [g*128 + (row^g)], g=k/8 in 0..7.
    // XOR swizzle keeps both staging writes and fragment reads conflict-free.
    __shared__ f16x8 As[8 * BM];   // 16 KB
    __shared__ f16x8 Bs[8 * BM];   // 16 KB

    const int tid  = threadIdx.x;
    const int lane = tid & 63;
    const int w    = tid >> 6;
    const int p    = blockIdx.x;
    const int bb   = (p & 7) * TPB + (p >> 3);   // XCD-chunked swizzle (T1)
    const int b    = bb / TPB;                   // == p & 7 (batch pinned to XCD)
    int t = bb - b * TPB;
    int ti = 0;
    while (t >= NT - ti) { t -= NT - ti; ++ti; }
    const int tj = ti + t;

    const float* embA = emb + ((size_t)b * NTOK + (size_t)ti * BM) * DIM;
    const float* embB = emb + ((size_t)b * NTOK + (size_t)tj * BM) * DIM;

    // ---- staging: global f32 -> LDS f16, prescaled by SQRTC2 (R0 pattern,
    // proven equal-cost to DMA in R2/R3; prescale is a free v_mul in cvt) ----
    {
        const int g  = tid & 7;     // k-group: k = 8g..8g+7
        const int r0 = tid >> 3;    // 0..31
#pragma unroll
        for (int pp = 0; pp < 4; ++pp) {
            const int row = r0 + 32 * pp;
            const float4 a0 = *(const float4*)(embA + (size_t)row * DIM + g * 8);
            const float4 a1 = *(const float4*)(embA + (size_t)row * DIM + g * 8 + 4);
            const float4 b0 = *(const float4*)(embB + (size_t)row * DIM + g * 8);
            const float4 b1 = *(const float4*)(embB + (size_t)row * DIM + g * 8 + 4);
            f16x8 pa, pb;
            pa[0] = (_Float16)(a0.x * SQRTC2); pa[1] = (_Float16)(a0.y * SQRTC2);
            pa[2] = (_Float16)(a0.z * SQRTC2); pa[3] = (_Float16)(a0.w * SQRTC2);
            pa[4] = (_Float16)(a1.x * SQRTC2); pa[5] = (_Float16)(a1.y * SQRTC2);
            pa[6] = (_Float16)(a1.z * SQRTC2); pa[7] = (_Float16)(a1.w * SQRTC2);
            pb[0] = (_Float16)(b0.x * SQRTC2); pb[1] = (_Float16)(b0.y * SQRTC2);
            pb[2] = (_Float16)(b0.z * SQRTC2); pb[3] = (_Float16)(b0.w * SQRTC2);
            pb[4] = (_Float16)(b1.x * SQRTC2); pb[5] = (_Float16)(b1.y * SQRTC2);
            pb[6] = (_Float16)(b1.z * SQRTC2); pb[7] = (_Float16)(b1.w * SQRTC2);
            As[g * BM + (row ^ g)] = pa;
            Bs[g * BM + (row ^ g)] = pb;
        }
    }
    __syncthreads();

    // ---- MFMA: wave computes a 64x64 subtile (2x2 of 32x32, K=64);
    // 16 ds_read_b128, 4 independent MFMA chains ----
    const int half = lane >> 5;    // k-half within fragment
    const int ln31 = lane & 31;
    const int waveR = (w & 1) * 64;
    const int waveC = (w >> 1) * 64;

    f32x16 acc00 = {}, acc01 = {}, acc10 = {}, acc11 = {};
#pragma unroll
    for (int s = 0; s < 4; ++s) {
        const int g = 2 * s + half;
        const f16x8 a0 = As[g * BM + ((waveR + ln31) ^ g)];
        const f16x8 a1 = As[g * BM + ((waveR + 32 + ln31) ^ g)];
        const f16x8 b0 = Bs[g * BM + ((waveC + ln31) ^ g)];
        const f16x8 b1 = Bs[g * BM + ((waveC + 32 + ln31) ^ g)];
        acc00 = __builtin_amdgcn_mfma_f32_32x32x16_f16(a0, b0, acc00, 0, 0, 0);
        acc01 = __builtin_amdgcn_mfma_f32_32x32x16_f16(a0, b1, acc01, 0, 0, 0);
        acc10 = __builtin_amdgcn_mfma_f32_32x32x16_f16(a1, b0, acc10, 0, 0, 0);
        acc11 = __builtin_amdgcn_mfma_f32_32x32x16_f16(a1, b1, acc11, 0, 0, 0);
    }

    // ---- epilogue: acc IS the log2-domain logit -> exp2 + add only.
    // Range (R10 analysis): acc in [-87, +87]; partial sums <= 2^99; f32-safe.
    float s0 = 0.f, s1 = 0.f, s2 = 0.f, s3 = 0.f;
#pragma unroll
    for (int e = 0; e < 16; ++e) {
        s0 += EXP2(acc00[e]);
        s1 += EXP2(acc01[e]);
        s2 += EXP2(acc10[e]);
        s3 += EXP2(acc11[e]);
    }
    float lsum = (s0 + s1) + (s2 + s3);
#pragma unroll
    for (int off = 32; off > 0; off >>= 1)
        lsum += __shfl_xor(lsum, off);

    if (lane == 0) {
        const float wgt = (ti == tj) ? 1.f : 2.f;
        ws[4 * (size_t)bb + w] = wgt * lsum;   // logical-bb layout for reduce
    }
}

// ---- kernel 2: 1 block, 8 waves; wave w sums batch w's TPB*4 = 2112 wave
// partials (weights already applied); 2112 = 33*64, fully static unroll.
__global__ __launch_bounds__(512)
void reduce_lse(const float* __restrict__ ws, float* __restrict__ out) {
    const int tid  = threadIdx.x;
    const int w    = tid >> 6;
    const int lane = tid & 63;
    __shared__ float lse8[BATCH];

    const float* p = ws + (size_t)w * TPB * 4;   // batch w: 2112 floats
    float s = 0.f;
#pragma unroll
    for (int c = 0; c < 33; ++c) s += p[lane + 64 * c];
#pragma unroll
    for (int off = 32; off > 0; off >>= 1) s += __shfl_xor(s, off);

    if (lane == 0) lse8[w] = LN2 * log2f(s);     // natural-log LSE
    __syncthreads();
    if (tid == 0) {
        float a = 0.f;
        for (int i = 0; i < BATCH; ++i) a += lse8[i];
        out[0] = a * (1.f / BATCH);
    }
}

extern "C" void kernel_launch(void* const* d_in, const int* in_sizes, int n_in,
                              void* d_out, int out_size, void* d_ws, size_t ws_size,
                              hipStream_t stream) {
    const float* emb = (const float*)d_in[0];
    float* out = (float*)d_out;
    float* prt = (float*)d_ws;     // BATCH*TPB*4 floats = 67,584 B partials

    gram_lse_partial<<<TOTAL, 256, 0, stream>>>(emb, prt);
    reduce_lse<<<1, 512, 0, stream>>>(prt, out);
}

// Round 13
// 75.914 us; speedup vs baseline: 1.2010x; 1.0046x over previous
//
#include <hip/hip_runtime.h>
#include <math.h>

#define BATCH 8
#define NTOK  4096
#define DIM   64
#define BM    128
#define NT    (NTOK / BM)            // 32 tiles per dim
#define TPB   (NT * (NT + 1) / 2)    // 528 upper-tri tile pairs per batch
#define TOTAL (BATCH * TPB)          // 4224 tile-pair blocks
#define KAPPA 0.5f
#define LOG2E 1.4426950408889634f
#define LN2   0.6931471805599453f
// sqrt(KAPPA*LOG2E): staging pre-scale so MFMA output IS the log2-domain logit
#define SQRTC2 0.8493218f

typedef _Float16 f16x8 __attribute__((ext_vector_type(8)));
typedef float    f32x16 __attribute__((ext_vector_type(16)));

__device__ __forceinline__ float EXP2(float x) {
#if __has_builtin(__builtin_amdgcn_exp2f)
    return __builtin_amdgcn_exp2f(x);
#else
    return __expf(x * LN2);
#endif
}

// ---- kernel 1: gram (R13 = R12 + MFMA/exp software pipeline).
// R12 budget: 76.3 = fill 41 (harness-fixed) + gram ~17-19 + reduce ~2.5 +
// ~8-10 boundary/restore. Gram's VALU/trans floor is ~6 us; the 2.5-3x gap
// is the per-wave serial phase chain (16 MFMAs THEN 64 exps). Fix: fully
// unrolled quadrant pipeline — fold(q) is issued after chain(q+1), so the
// exp burst (quarter-rate trans pipe) hides under the next quadrant's MFMA
// chain (separate pipe). Per-quadrant LDS reads (32 ds_read_b128/wave,
// R9-proven: conflict-free, port has headroom) keep live regs ~2 accs +
// 1 fragment set -> fits (256,5).
// Retained ledger: XOR-swizzled LDS (0 conflicts), XCD-chunked block swizzle
// (R5/R6: ~9-11 us), in-block cvt staging w/ SQRTC2 prescale (R12),
// exp2-only epilogue, (256,5): 5 blocks/CU, LDS 160 KB exact.
__global__ __launch_bounds__(256, 5)
void gram_lse_partial(const float* __restrict__ emb, float* __restrict__ ws) {
    // Panels as 16-B units: unit (g, row) at [g*128 + (row^g)], g=k/8 in 0..7.
    __shared__ f16x8 As[8 * BM];   // 16 KB
    __shared__ f16x8 Bs[8 * BM];   // 16 KB

    const int tid  = threadIdx.x;
    const int lane = tid & 63;
    const int w    = tid >> 6;
    const int p    = blockIdx.x;
    const int bb   = (p & 7) * TPB + (p >> 3);   // XCD-chunked swizzle (T1)
    const int b    = bb / TPB;                   // == p & 7 (batch pinned to XCD)
    int t = bb - b * TPB;
    int ti = 0;
    while (t >= NT - ti) { t -= NT - ti; ++ti; }
    const int tj = ti + t;

    const float* embA = emb + ((size_t)b * NTOK + (size_t)ti * BM) * DIM;
    const float* embB = emb + ((size_t)b * NTOK + (size_t)tj * BM) * DIM;

    // ---- staging: global f32 -> LDS f16, prescaled by SQRTC2 ----
    {
        const int g  = tid & 7;     // k-group: k = 8g..8g+7
        const int r0 = tid >> 3;    // 0..31
#pragma unroll
        for (int pp = 0; pp < 4; ++pp) {
            const int row = r0 + 32 * pp;
            const float4 a0 = *(const float4*)(embA + (size_t)row * DIM + g * 8);
            const float4 a1 = *(const float4*)(embA + (size_t)row * DIM + g * 8 + 4);
            const float4 b0 = *(const float4*)(embB + (size_t)row * DIM + g * 8);
            const float4 b1 = *(const float4*)(embB + (size_t)row * DIM + g * 8 + 4);
            f16x8 pa, pb;
            pa[0] = (_Float16)(a0.x * SQRTC2); pa[1] = (_Float16)(a0.y * SQRTC2);
            pa[2] = (_Float16)(a0.z * SQRTC2); pa[3] = (_Float16)(a0.w * SQRTC2);
            pa[4] = (_Float16)(a1.x * SQRTC2); pa[5] = (_Float16)(a1.y * SQRTC2);
            pa[6] = (_Float16)(a1.z * SQRTC2); pa[7] = (_Float16)(a1.w * SQRTC2);
            pb[0] = (_Float16)(b0.x * SQRTC2); pb[1] = (_Float16)(b0.y * SQRTC2);
            pb[2] = (_Float16)(b0.z * SQRTC2); pb[3] = (_Float16)(b0.w * SQRTC2);
            pb[4] = (_Float16)(b1.x * SQRTC2); pb[5] = (_Float16)(b1.y * SQRTC2);
            pb[6] = (_Float16)(b1.z * SQRTC2); pb[7] = (_Float16)(b1.w * SQRTC2);
            As[g * BM + (row ^ g)] = pa;
            Bs[g * BM + (row ^ g)] = pb;
        }
    }
    __syncthreads();

    // ---- quadrant pipeline: chain(q+1) issued before fold(q) ----
    const int half = lane >> 5;    // k-half within fragment
    const int ln31 = lane & 31;
    const int rA = (w & 1) * 64 + ln31;    // A rows: rA, rA+32
    const int rB = (w >> 1) * 64 + ln31;   // B rows: rB, rB+32

    float s0 = 0.f, s1 = 0.f, s2 = 0.f, s3 = 0.f;

    auto chain = [&](int ra, int rb) -> f32x16 {
        f32x16 acc = {};
#pragma unroll
        for (int s = 0; s < 4; ++s) {
            const int g = 2 * s + half;
            acc = __builtin_amdgcn_mfma_f32_32x32x16_f16(
                As[g * BM + (ra ^ g)], Bs[g * BM + (rb ^ g)], acc, 0, 0, 0);
        }
        return acc;
    };
    auto fold = [&](const f32x16& acc) {
#pragma unroll
        for (int e = 0; e < 16; e += 4) {
            s0 += EXP2(acc[e]);     s1 += EXP2(acc[e + 1]);
            s2 += EXP2(acc[e + 2]); s3 += EXP2(acc[e + 3]);
        }
    };

    f32x16 q0 = chain(rA,      rB);
    f32x16 q1 = chain(rA,      rB + 32);
    fold(q0);                              // exps overlap q1's MFMA tail
    f32x16 q2 = chain(rA + 32, rB);
    fold(q1);                              // exps overlap q2's MFMA
    f32x16 q3 = chain(rA + 32, rB + 32);
    fold(q2);                              // exps overlap q3's MFMA
    fold(q3);

    float lsum = (s0 + s1) + (s2 + s3);
#pragma unroll
    for (int off = 32; off > 0; off >>= 1)
        lsum += __shfl_xor(lsum, off);

    if (lane == 0) {
        const float wgt = (ti == tj) ? 1.f : 2.f;
        ws[4 * (size_t)bb + w] = wgt * lsum;   // logical-bb layout for reduce
    }
}

// ---- kernel 2: 1 block, 8 waves; wave w sums batch w's TPB*4 = 2112 wave
// partials (weights already applied); 2112 = 33*64, fully static unroll.
// Partials are plain sums of exp2(log2-domain logits); sums <= 2^99, f32-safe.
__global__ __launch_bounds__(512)
void reduce_lse(const float* __restrict__ ws, float* __restrict__ out) {
    const int tid  = threadIdx.x;
    const int w    = tid >> 6;
    const int lane = tid & 63;
    __shared__ float lse8[BATCH];

    const float* p = ws + (size_t)w * TPB * 4;   // batch w: 2112 floats
    float s = 0.f;
#pragma unroll
    for (int c = 0; c < 33; ++c) s += p[lane + 64 * c];
#pragma unroll
    for (int off = 32; off > 0; off >>= 1) s += __shfl_xor(s, off);

    if (lane == 0) lse8[w] = LN2 * log2f(s);     // natural-log LSE
    __syncthreads();
    if (tid == 0) {
        float a = 0.f;
        for (int i = 0; i < BATCH; ++i) a += lse8[i];
        out[0] = a * (1.f / BATCH);
    }
}

extern "C" void kernel_launch(void* const* d_in, const int* in_sizes, int n_in,
                              void* d_out, int out_size, void* d_ws, size_t ws_size,
                              hipStream_t stream) {
    const float* emb = (const float*)d_in[0];
    float* out = (float*)d_out;
    float* prt = (float*)d_ws;     // BATCH*TPB*4 floats = 67,584 B partials

    gram_lse_partial<<<TOTAL, 256, 0, stream>>>(emb, prt);
    reduce_lse<<<1, 512, 0, stream>>>(prt, out);
}